// Round 6
// baseline (196.761 us; speedup 1.0000x reference)
//
#include <hip/hip_runtime.h>
#include <hip/hip_bf16.h>

#define KT 32
#define START_TAG 30
#define END_TAG 31
#define NT 32   // timesteps per staged feat tile

__device__ __forceinline__ float exp2f_fast(float x){ return __builtin_amdgcn_exp2f(x); }
__device__ __forceinline__ float log2f_fast(float x){ return __builtin_amdgcn_logf(x); }  // v_log_f32 = log2
__device__ __forceinline__ float readlane_f(float v, int l){
    return __int_as_float(__builtin_amdgcn_readlane(__float_as_int(v), l));
}

// ONE sequence per 64-lane wave (lanes 32-63 mirror lanes 0-31; k = lane&31).
// Prob-domain CRF forward; the per-step 32-wide all-gather of alpha is done with
// v_readlane -> SGPR broadcast feeding FMA directly: NO memory op in the recurrence.
// Exact power-of-2 renorm every step (exponent of p0, integer M bookkeeping).
// Feats staged via double-buffered 32-step LDS tiles (issue at step 0, write at
// step 30, consumed >=3 steps later) so HBM latency is never on the critical path.
__global__ __launch_bounds__(64) void crf_nll(
    const float* __restrict__ feats,   // [B,T,K] f32
    const float* __restrict__ trans,   // [K,K]   f32, trans[next][prev]
    const int*   __restrict__ tags,    // [B,T]
    const int*   __restrict__ masks,   // [B,T]
    float* __restrict__ out, int B, int T)
{
    constexpr float L2E = 1.4426950408889634f;
    constexpr float LN2 = 0.6931471805599453f;
    const int lane = (int)threadIdx.x;
    const int k = lane & 31;
    const int b = (int)blockIdx.x;     // grid = B

    __shared__ float  Tl[KT * KT];                   // transitions (gold lookups)
    __shared__ __align__(16) float ftile[2][NT][KT]; // feat double-buffer

    for (int i = lane; i < KT * KT; i += 64) Tl[i] = trans[i];

    // Per-lane row of E = exp(trans). INVALID(-1e4) -> 0 exactly.
    float E[KT];
#pragma unroll
    for (int j = 0; j < KT; ++j) E[j] = exp2f_fast(trans[k * KT + j] * L2E);
    const float E2 = exp2f_fast(trans[END_TAG * KT + k] * L2E);

    __syncthreads();

    // ---------- feat tile machinery: tile = 32 steps x 32 floats = 256 float4 ----------
    const float4* f4 = (const float4*)(feats + (size_t)b * T * KT);
    float4 R[4];
#define TLOAD(ti) { const int o = (ti) * 256 + lane;                           \
    R[0]=f4[o]; R[1]=f4[o+64]; R[2]=f4[o+128]; R[3]=f4[o+192]; }
#define TWRITE(buf) { float4* w = (float4*)&ftile[buf][0][0];                  \
    w[lane]=R[0]; w[lane+64]=R[1]; w[lane+128]=R[2]; w[lane+192]=R[3]; }
#define FEAT(t) ftile[((t) >> 5) & 1][(t) & 31][k]

    TLOAD(0)   // overlap tile-0 fetch with the gold phase

    // ---------- gold score + length (all 64 lanes, stride 64 over t) ----------
    const int*   tg = tags  + (size_t)b * T;
    const int*   mk = masks + (size_t)b * T;
    const float* fb = feats + (size_t)b * T * KT;
    float g = 0.f;
    int   Lp = 0;
    for (int c = 0; c < T; c += 64) {
        const int t = c + lane;
        if (t < T) {
            const int mt = mk[t];
            Lp += mt;
            const int tagt  = tg[t];
            const int prev  = t ? tg[t - 1] : START_TAG;
            const int fprev = t ? mk[t - 1] : 1;
            if (mt)    g += fb[(size_t)t * KT + tagt];
            if (fprev) g += Tl[tagt * KT + prev];
            if (t == T - 1 && mt) g += Tl[END_TAG * KT + tagt];
        }
    }
#pragma unroll
    for (int d = 1; d < 64; d <<= 1) { g += __shfl_xor(g, d); Lp += __shfl_xor(Lp, d); }
    const int L = Lp;                       // wave-uniform (>=1)

    // prologue staging: tile0 -> buf0, tile1 -> buf1
    TWRITE(0)
    const int ntiles = T >> 5;              // T = 512 -> 16
    if (ntiles > 1) { TLOAD(1) TWRITE(1) }

    // ---------- init DP ----------
    float y = (k == START_TAG) ? 1.f : 0.f;
    int M = 0;

    // feat register pipeline, depth 3 (LDS-backed): consume Fc=exp(feat[t]) at step t
    float Fc = exp2f_fast(FEAT(0) * L2E);
    float f1 = FEAT(1);
    float f2 = FEAT(2);

    const int nact = (L + NT - 1) >> 5;
    for (int n = 0; n < nact; ++n) {
        const int tb = n << 5;
#pragma unroll
        for (int ti_ = 0; ti_ < NT; ++ti_) {
            const int t = tb + ti_;
            if (ti_ == 0)  { const int nx = n + 2; if (nx < ntiles) TLOAD(nx) }
            // all-gather alpha via readlane (SGPR broadcast), FMA into 4 accumulators
            float a0 = 0.f, a1 = 0.f, a2 = 0.f, a3 = 0.f;
#pragma unroll
            for (int j = 0; j < KT; j += 4) {
                a0 = fmaf(E[j+0], readlane_f(y, j+0), a0);
                a1 = fmaf(E[j+1], readlane_f(y, j+1), a1);
                a2 = fmaf(E[j+2], readlane_f(y, j+2), a2);
                a3 = fmaf(E[j+3], readlane_f(y, j+3), a3);
            }
            // exact power-of-2 renorm from p0's exponent (overlaps with FMA issue)
            const unsigned pb = __float_as_uint(readlane_f(y, 0));
            int e = (int)((pb >> 23) & 255u);
            if (e < 1 || e > 253) e = 127;
            const float Fcr = Fc * __uint_as_float((unsigned)(254 - e) << 23);
            const float val = ((a0 + a1) + (a2 + a3)) * Fcr;
            const bool act = t < L;          // wave-uniform freeze for tail of last tile
            y  = act ? val : y;
            M += act ? (e - 127) : 0;
            if (ti_ == 30) { const int nx = n + 2; if (nx < ntiles) TWRITE(n & 1) }
            // rotate feat pipeline: raw feat(t+3) from LDS (consumed at step t+3)
            const float fnew = FEAT(t + 3);  // may be stale past L; discarded via act
            Fc = exp2f_fast(f1 * L2E);
            f1 = f2;
            f2 = fnew;
        }
    }

    // terminal: Z = ln2 * (M + log2(sum_k y[k] * E2[k]))
    float term = y * E2;
#pragma unroll
    for (int d = 1; d < 32; d <<= 1) term += __shfl_xor(term, d);
    const float Z = ((float)M + log2f_fast(term)) * LN2;

    if (lane == 0) out[b] = Z - g;
#undef TLOAD
#undef TWRITE
#undef FEAT
}

extern "C" void kernel_launch(void* const* d_in, const int* in_sizes, int n_in,
                              void* d_out, int out_size, void* d_ws, size_t ws_size,
                              hipStream_t stream) {
    const float* feats = (const float*)d_in[0];
    const float* trans = (const float*)d_in[1];
    const int*   tags  = (const int*)d_in[2];
    const int*   masks = (const int*)d_in[3];
    float* out = (float*)d_out;

    const int B = out_size;                 // 1024
    const int T = in_sizes[2] / B;          // 512

    hipLaunchKernelGGL(crf_nll, dim3(B), dim3(64), 0, stream,
                       feats, trans, tags, masks, out, B, T);
}

// Round 7
// 167.887 us; speedup vs baseline: 1.1720x; 1.1720x over previous
//
#include <hip/hip_runtime.h>

#define KT 32
#define START_TAG 30
#define END_TAG 31

__device__ __forceinline__ float exp2f_fast(float x){ return __builtin_amdgcn_exp2f(x); }
__device__ __forceinline__ float log2f_fast(float x){ return __builtin_amdgcn_logf(x); }  // v_log_f32 = log2
__device__ __forceinline__ float readlane_f(float v, int l){
    return __int_as_float(__builtin_amdgcn_readlane(__float_as_int(v), l));
}

// One 128-thread block per sequence: wave 0 runs the FORWARD prob-domain DP for
// mf=ceil(L/2) steps; wave 1 runs the BACKWARD DP (E^T, init exp(trans[END][k]))
// for L-mf steps (+ gold score); combine Z = ln2*(MF+MB+log2(sum alpha*beta)).
// 2048 chains of <=256 steps (2 waves/SIMD: stalls cross-hidden). Per step the
// 32-wide all-gather is v_readlane->SGPR (all 32 grouped, sched_barrier, then 32
// FMAs: hazard distance >=32). Exact power-of-2 renorm each step (integer M).
// Feats staged via double-buffered 32-step LDS tiles, prefetched 2 tiles ahead.
__global__ __launch_bounds__(128, 2) void crf_nll(
    const float* __restrict__ feats,   // [B,T,K] f32
    const float* __restrict__ trans,   // [K,K]   f32, trans[next][prev]
    const int*   __restrict__ tags,    // [B,T]
    const int*   __restrict__ masks,   // [B,T]
    float* __restrict__ out, int B, int T)
{
    constexpr float L2E = 1.4426950408889634f;
    constexpr float LN2 = 0.6931471805599453f;
    const int tid  = (int)threadIdx.x;
    const int lane = tid & 63;
    const int wid  = tid >> 6;        // 0 = forward, 1 = backward(+gold)
    const int k    = lane & 31;
    const int b    = (int)blockIdx.x;

    __shared__ float Tl[KT * KT];                        // transitions (gold)
    __shared__ __align__(16) float ftile[2][2][32][KT];  // [wave][buf][row][k]
    __shared__ float cvec[KT];                           // alpha at meeting point
    __shared__ int   cMF;

    for (int i = tid; i < KT * KT; i += 128) Tl[i] = trans[i];

    // E rows: fwd lane k holds E[k][j]=exp(trans[k][j]); bwd lane j holds E^T[j][m]=exp(trans[m][j])
    float E[KT];
    float E2 = 0.f;
    if (wid == 0) {
#pragma unroll
        for (int j = 0; j < KT; ++j) E[j] = exp2f_fast(trans[k * KT + j] * L2E);
    } else {
#pragma unroll
        for (int m = 0; m < KT; ++m) E[m] = exp2f_fast(trans[m * KT + k] * L2E);
        E2 = exp2f_fast(trans[END_TAG * KT + k] * L2E);
    }
    __syncthreads();   // Tl ready (bwd gold needs it)

    const float4* f4 = (const float4*)(feats + (size_t)b * T * KT);
    const int*    mk = masks + (size_t)b * T;
    const int*    tg = tags  + (size_t)b * T;
    const float*  fb = feats + (size_t)b * T * KT;

    // ---- length L (each wave independently; wave-uniform) ----
    int Lp = 0;
    for (int c = 0; c < T; c += 64) { const int t = c + lane; if (t < T) Lp += mk[t]; }
#pragma unroll
    for (int d = 1; d < 64; d <<= 1) Lp += __shfl_xor(Lp, d);
    const int L   = Lp;                 // >= 1
    const int mf  = (L + 1) >> 1;       // fwd steps; bwd steps = L - mf
    const int ntT = T >> 5;

    float4 R0, R1, R2, R3, S0, S1, S2, S3;
    float y = 0.f, Fc = 0.f, f1 = 0.f, f2 = 0.f, g = 0.f;
    int   M = 0;

#define TLOADR(ti_) { const int o=(ti_)*256+lane; R0=f4[o];R1=f4[o+64];R2=f4[o+128];R3=f4[o+192]; }
#define TLOADS(ti_) { const int o=(ti_)*256+lane; S0=f4[o];S1=f4[o+64];S2=f4[o+128];S3=f4[o+192]; }
#define TWRITER(bf) { float4* w=(float4*)&ftile[wid][bf][0][0]; w[lane]=R0;w[lane+64]=R1;w[lane+128]=R2;w[lane+192]=R3; }
#define TWRITES(bf) { float4* w=(float4*)&ftile[wid][bf][0][0]; w[lane]=S0;w[lane+64]=S1;w[lane+128]=S2;w[lane+192]=S3; }
#define FEAT(t_) ftile[wid][((t_)>>5)&1][(t_)&31][k]

    if (wid == 0) {
        // ================= FORWARD WAVE =================
        TLOADR(0)
        if (ntT > 1) TLOADS(1)
        TWRITER(0)
        if (ntT > 1) TWRITES(1)
        y  = (k == START_TAG) ? 1.f : 0.f;
        Fc = exp2f_fast(FEAT(0) * L2E);
        f1 = FEAT(1);
        f2 = FEAT(2);
        const int ntA = (mf + 31) >> 5;
        for (int n = 0; n < ntA; ++n) {
            for (int c = 0; c < 4; ++c) {
#pragma unroll
                for (int u = 0; u < 8; ++u) {
                    const int ti_ = c * 8 + u;
                    const int t   = (n << 5) + ti_;
                    if (ti_ == 0)  { const int nx = n + 2; if (nx < ntA) TLOADR(nx) }
                    float sv[32];
#pragma unroll
                    for (int j = 0; j < 32; ++j) sv[j] = readlane_f(y, j);
                    __builtin_amdgcn_sched_barrier(0);
                    const unsigned pb = __float_as_uint(sv[0]);
                    int e = (int)((pb >> 23) & 255u);
                    if (e < 1 || e > 253) e = 127;
                    const float Fcr = Fc * __uint_as_float((unsigned)(254 - e) << 23);
                    float a0 = 0.f, a1 = 0.f, a2 = 0.f, a3 = 0.f;
#pragma unroll
                    for (int j = 0; j < 32; j += 4) {
                        a0 = fmaf(E[j+0], sv[j+0], a0);
                        a1 = fmaf(E[j+1], sv[j+1], a1);
                        a2 = fmaf(E[j+2], sv[j+2], a2);
                        a3 = fmaf(E[j+3], sv[j+3], a3);
                    }
                    const float val = ((a0 + a1) + (a2 + a3)) * Fcr;
                    const bool act = t < mf;
                    y  = act ? val : y;
                    M += act ? (e - 127) : 0;
                    if (ti_ == 30) { const int nx = n + 2; if (nx < ntA) TWRITER((n & 1)) }
                    const float fnew = FEAT(t + 3);
                    Fc = exp2f_fast(f1 * L2E);
                    f1 = f2; f2 = fnew;
                }
            }
        }
        if (lane < 32) cvec[k] = y;
        if (tid == 0) cMF = M;
    } else {
        // ================= BACKWARD WAVE (+ gold) =================
        const int n_hi = (L - 1) >> 5;
        const int n_lo = mf >> 5;
        TLOADR(n_hi)
        if (n_hi >= 1) TLOADS(n_hi - 1)
        float4 Q0, Q1, Q2, Q3;
        if (n_hi >= 2) { const int o=(n_hi-2)*256+lane; Q0=f4[o];Q1=f4[o+64];Q2=f4[o+128];Q3=f4[o+192]; }

        // gold score (overlaps staging-load latency)
        for (int c = 0; c < T; c += 64) {
            const int t = c + lane;
            if (t < T) {
                const int mt    = mk[t];
                const int tagt  = tg[t];
                const int prev  = t ? tg[t - 1] : START_TAG;
                const int fprev = t ? mk[t - 1] : 1;
                if (mt)    g += fb[(size_t)t * KT + tagt];
                if (fprev) g += Tl[tagt * KT + prev];
                if (t == T - 1 && mt) g += Tl[END_TAG * KT + tagt];
            }
        }
#pragma unroll
        for (int d = 1; d < 64; d <<= 1) g += __shfl_xor(g, d);

        TWRITER((n_hi & 1))
        if (n_hi >= 1) TWRITES(((n_hi - 1) & 1))
        y = E2; M = 0;
        Fc = exp2f_fast(FEAT(L - 1) * L2E);
        f1 = FEAT(L - 2);      // may be garbage for tiny L; masked by act
        f2 = FEAT(L - 3);

#define BSTEP(T_, DO_LD, LD_TI, DO_WR, WR_BF) {                               \
        if (DO_LD) TLOADR(LD_TI)                                              \
        const float bb = y * Fc;                                              \
        float sv[32];                                                         \
        _Pragma("unroll")                                                     \
        for (int j = 0; j < 32; ++j) sv[j] = readlane_f(bb, j);               \
        __builtin_amdgcn_sched_barrier(0);                                    \
        const unsigned pb = __float_as_uint(sv[0]);                           \
        int e = (int)((pb >> 23) & 255u);                                     \
        if (e < 1 || e > 253) e = 127;                                        \
        const float r = __uint_as_float((unsigned)(254 - e) << 23);           \
        float a0 = 0.f, a1 = 0.f, a2 = 0.f, a3 = 0.f;                         \
        _Pragma("unroll")                                                     \
        for (int j = 0; j < 32; j += 4) {                                     \
            a0 = fmaf(E[j+0], sv[j+0], a0);                                   \
            a1 = fmaf(E[j+1], sv[j+1], a1);                                   \
            a2 = fmaf(E[j+2], sv[j+2], a2);                                   \
            a3 = fmaf(E[j+3], sv[j+3], a3);                                   \
        }                                                                     \
        const float val = ((a0 + a1) + (a2 + a3)) * r;                        \
        const bool act = (T_) >= mf;                                          \
        y  = act ? val : y;                                                   \
        M += act ? (e - 127) : 0;                                             \
        if (DO_WR) TWRITER(WR_BF)                                             \
        const float fnew = FEAT((T_) - 3);                                    \
        Fc = exp2f_fast(f1 * L2E);                                            \
        f1 = f2; f2 = fnew; }

        // peel: t = L-1 down to 32*n_hi (no staging ops)
        for (int t = L - 1; t >= (n_hi << 5); --t) {
            BSTEP(t, false, 0, false, 0)
        }
        // tile n_hi's buffer is now dead: park tile n_hi-2 there
        if (n_hi >= 2) { float4* w=(float4*)&ftile[wid][(n_hi & 1)][0][0];
                         w[lane]=Q0;w[lane+64]=Q1;w[lane+128]=Q2;w[lane+192]=Q3; }
        // main tiles, descending
        for (int n = n_hi - 1; n >= n_lo; --n) {
            for (int c = 0; c < 4; ++c) {
#pragma unroll
                for (int u = 0; u < 8; ++u) {
                    const int ti_ = c * 8 + u;
                    const int t   = (n << 5) + 31 - ti_;
                    BSTEP(t, (ti_ == 0) && (n >= n_lo + 2), n - 2,
                             (ti_ == 29) && (n >= n_lo + 2), (n & 1))
                }
            }
        }
#undef BSTEP
    }

    __syncthreads();
    if (wid == 1) {
        float term = y * cvec[k];          // beta_hat * alpha_hat at meeting point
#pragma unroll
        for (int d = 1; d < 32; d <<= 1) term += __shfl_xor(term, d);
        const float Z = ((float)(M + cMF) + log2f_fast(term)) * LN2;
        if (lane == 0) out[b] = Z - g;
    }
#undef TLOADR
#undef TLOADS
#undef TWRITER
#undef TWRITES
#undef FEAT
}

extern "C" void kernel_launch(void* const* d_in, const int* in_sizes, int n_in,
                              void* d_out, int out_size, void* d_ws, size_t ws_size,
                              hipStream_t stream) {
    const float* feats = (const float*)d_in[0];
    const float* trans = (const float*)d_in[1];
    const int*   tags  = (const int*)d_in[2];
    const int*   masks = (const int*)d_in[3];
    float* out = (float*)d_out;

    const int B = out_size;                 // 1024
    const int T = in_sizes[2] / B;          // 512

    hipLaunchKernelGGL(crf_nll, dim3(B), dim3(128), 0, stream,
                       feats, trans, tags, masks, out, B, T);
}

// Round 8
// 152.751 us; speedup vs baseline: 1.2881x; 1.0991x over previous
//
#include <hip/hip_runtime.h>

#define KT 32
#define START_TAG 30
#define END_TAG 31

__device__ __forceinline__ float exp2f_fast(float x){ return __builtin_amdgcn_exp2f(x); }
__device__ __forceinline__ float log2f_fast(float x){ return __builtin_amdgcn_logf(x); }  // v_log_f32 = log2

// Broadcast the value held by group-lane J (0..31) of each 32-lane half to all
// lanes of that half. BitMode swizzle: new_lane = ((lane & 0) | J) ^ 0 = J.
#define SWZB(v, J) __int_as_float(__builtin_amdgcn_ds_swizzle(__float_as_int(v), ((J) << 5)))

// One 128-thread block per sequence. Wave 0: FORWARD prob-domain DP, mf=ceil(L/2)
// steps. Wave 1: BACKWARD DP (E^T) for L-mf steps + gold score. Combine
// Z = ln2*(MF+MB+log2(0.5*sum_lanes alpha*beta)).
//
// Lane decomposition (the round-8 change): lane (h,i), h=lane>>5, i=lane&31 owns
// output index ok=(i+16h)&31 and accumulates only j in [16h,16h+16) (16 FMAs).
// Partner lane (lane^48) owns the same ok with the other j-half: one
// __shfl_xor(48) + add completes the dot. The 32-wide broadcast is 16 ds_swizzle
// or-mode broadcasts; the rotated upper-half ownership makes one swizzle
// immediate serve both halves (upper group-lane j holds alpha[16+j]).
// Exact power-of-2 renorm, anchor captured with 1-step lag (off critical path).
// Feats staged via double-buffered 32-step LDS tiles, 2 tiles ahead.
__global__ __launch_bounds__(128, 2) void crf_nll(
    const float* __restrict__ feats,   // [B,T,K] f32
    const float* __restrict__ trans,   // [K,K]   f32, trans[next][prev]
    const int*   __restrict__ tags,    // [B,T]
    const int*   __restrict__ masks,   // [B,T]
    float* __restrict__ out, int B, int T)
{
    constexpr float L2E = 1.4426950408889634f;
    constexpr float LN2 = 0.6931471805599453f;
    const int tid  = (int)threadIdx.x;
    const int lane = tid & 63;
    const int wid  = tid >> 6;        // 0 = forward, 1 = backward(+gold)
    const int li   = lane & 31;
    const int h    = lane >> 5;
    const int ok   = (li + (h << 4)) & 31;   // owned output row (fwd) / col (bwd)
    const int b    = (int)blockIdx.x;

    __shared__ float Tl[KT * KT];                        // transitions (gold)
    __shared__ __align__(16) float ftile[2][2][32][KT];  // [wave][buf][row][k]
    __shared__ float cvec[KT];                           // alpha at meeting point
    __shared__ int   cMF;

    for (int i = tid; i < KT * KT; i += 128) Tl[i] = trans[i];

    // Per-lane 16-entry E slice (prob domain; INVALID -> exactly 0).
    float Eh[16];
    if (wid == 0) {
        // fwd: row ok, cols [16h, 16h+16)
#pragma unroll
        for (int j = 0; j < 16; ++j)
            Eh[j] = exp2f_fast(trans[ok * KT + (h << 4) + j] * L2E);
    } else {
        // bwd: E^T row ok => column ok, rows [16h, 16h+16)
#pragma unroll
        for (int j = 0; j < 16; ++j)
            Eh[j] = exp2f_fast(trans[((h << 4) + j) * KT + ok] * L2E);
    }
    __syncthreads();   // Tl ready (gold needs it)

    const float4* f4 = (const float4*)(feats + (size_t)b * T * KT);
    const int*    mk = masks + (size_t)b * T;
    const int*    tg = tags  + (size_t)b * T;
    const float*  fb = feats + (size_t)b * T * KT;

    // ---- length L (wave-uniform) ----
    int Lp = 0;
    for (int c = 0; c < T; c += 64) { const int t = c + lane; if (t < T) Lp += mk[t]; }
#pragma unroll
    for (int d = 1; d < 64; d <<= 1) Lp += __shfl_xor(Lp, d);
    const int L  = Lp;                 // >= 1
    const int mf = (L + 1) >> 1;       // fwd steps; bwd steps = L - mf

    float4 R0, R1, R2, R3, S0, S1, S2, S3;
    float y = 0.f, Fcr = 0.f, f1 = 0.f, f2 = 0.f, g = 0.f;
    int   M = 0, dMp = 0;

#define TLOADR(ti_) { const int o=(ti_)*256+lane; R0=f4[o];R1=f4[o+64];R2=f4[o+128];R3=f4[o+192]; }
#define TLOADS(ti_) { const int o=(ti_)*256+lane; S0=f4[o];S1=f4[o+64];S2=f4[o+128];S3=f4[o+192]; }
#define TWRITER(bf) { float4* w=(float4*)&ftile[wid][bf][0][0]; w[lane]=R0;w[lane+64]=R1;w[lane+128]=R2;w[lane+192]=R3; }
#define TWRITES(bf) { float4* w=(float4*)&ftile[wid][bf][0][0]; w[lane]=S0;w[lane+64]=S1;w[lane+128]=S2;w[lane+192]=S3; }
#define FEAT(t_) ftile[wid][((t_)>>5)&1][(t_)&31][ok]

    // 16 broadcasts + 16 FMAs + xor48 combine => ss = full dot in owned layout
#define MATVEC(SRC, SS)                                                        \
    const float b0=SWZB(SRC,0),  b1=SWZB(SRC,1),  b2=SWZB(SRC,2),  b3=SWZB(SRC,3),  \
                b4=SWZB(SRC,4),  b5=SWZB(SRC,5),  b6=SWZB(SRC,6),  b7=SWZB(SRC,7),  \
                b8=SWZB(SRC,8),  b9=SWZB(SRC,9),  b10=SWZB(SRC,10),b11=SWZB(SRC,11),\
                b12=SWZB(SRC,12),b13=SWZB(SRC,13),b14=SWZB(SRC,14),b15=SWZB(SRC,15);\
    float a0 = Eh[0]*b0, a1 = Eh[1]*b1, a2 = Eh[2]*b2, a3 = Eh[3]*b3;          \
    a0 = fmaf(Eh[4], b4, a0);  a1 = fmaf(Eh[5], b5, a1);                       \
    a2 = fmaf(Eh[6], b6, a2);  a3 = fmaf(Eh[7], b7, a3);                       \
    a0 = fmaf(Eh[8], b8, a0);  a1 = fmaf(Eh[9], b9, a1);                       \
    a2 = fmaf(Eh[10],b10,a2);  a3 = fmaf(Eh[11],b11,a3);                       \
    a0 = fmaf(Eh[12],b12,a0);  a1 = fmaf(Eh[13],b13,a1);                       \
    a2 = fmaf(Eh[14],b14,a2);  a3 = fmaf(Eh[15],b15,a3);                       \
    const float pp = (a0 + a1) + (a2 + a3);                                    \
    const float SS = pp + __shfl_xor(pp, 48);

    // renorm capture (1-step lag): from ss derive next step's scale + dM
#define CAPTURE(SS)                                                            \
    { const int cap = __builtin_amdgcn_readfirstlane(__float_as_int(SS));      \
      int e = (cap >> 23) & 255; if (e < 1 || e > 253) e = 127;                \
      dMp = e - 127;                                                           \
      Fcr = exp2f_fast(f1 * L2E) * __uint_as_float((unsigned)(254 - e) << 23); }

    if (wid == 0) {
        // ================= FORWARD WAVE =================
        const int ntA = (mf + 31) >> 5;
        TLOADR(0)
        if (ntA > 1) TLOADS(1)
        TWRITER(0)
        if (ntA > 1) TWRITES(1)
        y   = (ok == START_TAG) ? 1.f : 0.f;
        Fcr = exp2f_fast(FEAT(0) * L2E);
        f1  = FEAT(1);
        f2  = FEAT(2);
        for (int n = 0; n < ntA; ++n) {
            for (int c = 0; c < 4; ++c) {
#pragma unroll
                for (int u = 0; u < 8; ++u) {
                    const int ti_ = c * 8 + u;
                    const int t   = (n << 5) + ti_;
                    if (ti_ == 0)  { const int nx = n + 2; if (nx < ntA) TLOADR(nx) }
                    const float fnew = FEAT(t + 3);
                    MATVEC(y, ss)
                    const float val = ss * Fcr;
                    const bool  act = t < mf;
                    y  = act ? val : y;
                    M += act ? dMp : 0;
                    CAPTURE(ss)
                    if (ti_ == 30) { const int nx = n + 2; if (nx < ntA) TWRITER((n & 1)) }
                    f1 = f2; f2 = fnew;
                }
            }
        }
        if (lane < 32) cvec[lane] = y;     // lane i holds alpha_i
        if (tid == 0)  cMF = M;
    } else {
        // ================= BACKWARD WAVE (+ gold) =================
        const int n_hi = (L - 1) >> 5;
        const int n_lo = mf >> 5;
        TLOADR(n_hi)
        if (n_hi >= 1) TLOADS(n_hi - 1)
        float4 Q0, Q1, Q2, Q3;
        if (n_hi >= 2) { const int o=(n_hi-2)*256+lane; Q0=f4[o];Q1=f4[o+64];Q2=f4[o+128];Q3=f4[o+192]; }

        // gold score (overlaps staging-load latency)
        for (int c = 0; c < T; c += 64) {
            const int t = c + lane;
            if (t < T) {
                const int mt    = mk[t];
                const int tagt  = tg[t];
                const int prev  = t ? tg[t - 1] : START_TAG;
                const int fprev = t ? mk[t - 1] : 1;
                if (mt)    g += fb[(size_t)t * KT + tagt];
                if (fprev) g += Tl[tagt * KT + prev];
                if (t == T - 1 && mt) g += Tl[END_TAG * KT + tagt];
            }
        }
#pragma unroll
        for (int d = 1; d < 64; d <<= 1) g += __shfl_xor(g, d);

        TWRITER((n_hi & 1))
        if (n_hi >= 1) TWRITES(((n_hi - 1) & 1))
        y   = exp2f_fast(trans[END_TAG * KT + ok] * L2E);   // beta init
        Fcr = exp2f_fast(FEAT(L - 1) * L2E);
        f1  = FEAT(L - 2);      // garbage for tiny L; masked via act
        f2  = FEAT(L - 3);

#define BSTEP(T_, DO_LD, LD_TI, DO_WR, WR_BF) {                               \
        if (DO_LD) TLOADR(LD_TI)                                              \
        const float fnew = FEAT((T_) - 3);                                    \
        const float bb = y * Fcr;                                             \
        MATVEC(bb, ss)                                                        \
        const bool act = (T_) >= mf;                                          \
        y  = act ? ss : y;                                                    \
        M += act ? dMp : 0;                                                   \
        CAPTURE(ss)                                                           \
        if (DO_WR) TWRITER(WR_BF)                                             \
        f1 = f2; f2 = fnew; }

        // peel: t = L-1 down to 32*n_hi (no staging ops)
        for (int t = L - 1; t >= (n_hi << 5); --t) {
            BSTEP(t, false, 0, false, 0)
        }
        // tile n_hi's buffer is dead now: park tile n_hi-2 there
        if (n_hi >= 2) { float4* w=(float4*)&ftile[wid][(n_hi & 1)][0][0];
                         w[lane]=Q0;w[lane+64]=Q1;w[lane+128]=Q2;w[lane+192]=Q3; }
        // main tiles, descending
        for (int n = n_hi - 1; n >= n_lo; --n) {
            for (int c = 0; c < 4; ++c) {
#pragma unroll
                for (int u = 0; u < 8; ++u) {
                    const int ti_ = c * 8 + u;
                    const int t   = (n << 5) + 31 - ti_;
                    BSTEP(t, (ti_ == 0) && (n >= n_lo + 2), n - 2,
                             (ti_ == 29) && (n >= n_lo + 2), (n & 1))
                }
            }
        }
#undef BSTEP
    }

    __syncthreads();
    if (wid == 1) {
        // each alpha_k*beta_k appears twice across the 64 lanes -> *0.5
        float term = y * cvec[ok];
#pragma unroll
        for (int d = 1; d < 64; d <<= 1) term += __shfl_xor(term, d);
        const float Z = ((float)(M + cMF) + log2f_fast(term * 0.5f)) * LN2;
        if (lane == 0) out[b] = Z - g;
    }
#undef TLOADR
#undef TLOADS
#undef TWRITER
#undef TWRITES
#undef FEAT
#undef MATVEC
#undef CAPTURE
}

extern "C" void kernel_launch(void* const* d_in, const int* in_sizes, int n_in,
                              void* d_out, int out_size, void* d_ws, size_t ws_size,
                              hipStream_t stream) {
    const float* feats = (const float*)d_in[0];
    const float* trans = (const float*)d_in[1];
    const int*   tags  = (const int*)d_in[2];
    const int*   masks = (const int*)d_in[3];
    float* out = (float*)d_out;

    const int B = out_size;                 // 1024
    const int T = in_sizes[2] / B;          // 512

    hipLaunchKernelGGL(crf_nll, dim3(B), dim3(128), 0, stream,
                       feats, trans, tags, masks, out, B, T);
}